// Round 2
// baseline (302.682 us; speedup 1.0000x reference)
//
#include <hip/hip_runtime.h>
#include <cstdint>

#define N_ 32
#define H_ 56
#define W_ 56
#define C_ 256
#define HP 58
#define WP 58

// ---------------- kernel 1: pack weight sign bits + |k| partial sums --------
// grid = 36 blocks (idx = p*4 + j, p = kh*3+kw in [0,9), j = word in [0,4))
// block = 256 threads (co). Reads coalesced across co. Fully unrolled for ILP.
__global__ __launch_bounds__(256) void pack_w(const float* __restrict__ k,
                                              uint64_t* __restrict__ kb,
                                              float* __restrict__ palpha) {
    int idx = blockIdx.x;            // 0..35
    int p = idx >> 2, j = idx & 3;
    int co = threadIdx.x;
    uint64_t bits = 0;
    float s = 0.f;
    #pragma unroll
    for (int b = 0; b < 64; ++b) {
        int ci = j * 64 + b;
        float v = k[(p * 256 + ci) * 256 + co];
        bits |= (uint64_t)(v > 0.f) << b;
        s += fabsf(v);
    }
    kb[idx * 256 + co] = bits;       // layout: kb[idx][co] -> coalesced in k3
    palpha[idx * 256 + co] = s;
}

// ---------------- kernel 2: pack input sign bits + beta ---------------------
// grid = N_*HP blocks (one padded row), block = 256 = 4 waves.
// Word w of a pixel = ballot over channels [64w, 64w+64). Border pixels: x=0
// -> sign bit 0 (sign(0) = -1 in the reference), beta contribution 0.
__global__ void pack_x(const float* __restrict__ x, uint64_t* __restrict__ xb,
                       float* __restrict__ beta) {
    int bi = blockIdx.x;             // n*HP + y (padded row)
    int n = bi / HP, y = bi % HP;
    int wave = threadIdx.x >> 6, lane = threadIdx.x & 63;
    for (int xc = wave; xc < WP; xc += 4) {
        bool inb = (y >= 1 && y <= H_ && xc >= 1 && xc <= W_);
        float v0 = 0.f, v1 = 0.f, v2 = 0.f, v3 = 0.f;
        if (inb) {
            const float* px = x + (((size_t)n * H_ + (y - 1)) * W_ + (xc - 1)) * C_;
            v0 = px[lane];
            v1 = px[64 + lane];
            v2 = px[128 + lane];
            v3 = px[192 + lane];
        }
        uint64_t m0 = __ballot(v0 > 0.f);
        uint64_t m1 = __ballot(v1 > 0.f);
        uint64_t m2 = __ballot(v2 > 0.f);
        uint64_t m3 = __ballot(v3 > 0.f);
        float s = fabsf(v0) + fabsf(v1) + fabsf(v2) + fabsf(v3);
        #pragma unroll
        for (int m = 32; m >= 1; m >>= 1) s += __shfl_xor(s, m, 64);
        size_t pix = (size_t)bi * WP + xc;
        if (lane < 4) {
            uint64_t mw = (lane == 0) ? m0 : (lane == 1) ? m1 : (lane == 2) ? m2 : m3;
            xb[pix * 4 + lane] = mw;
        }
        if (lane == 0) beta[pix] = s * (1.f / 256.f);
    }
}

// ---------------- kernel 3: binary conv via xor+popcount --------------------
// grid = N_*H_ blocks (one output row), block = 256 threads (thread = cout).
// LDS holds 3 padded input rows of packed bits (broadcast reads, conflict-free).
// Register-fit design (round 1 spilled kr[36]+acc[28] to AGPRs -> 2.5x VALU):
//   - 2 word-passes (jp): only 2 of 4 channel-words of the weights live at a
//     time (kr0[9]+kr1[9] = 36 VGPRs), reloaded from L2-resident kb per pass.
//   - 4 output chunks of 14 (acc[14] = 14 VGPRs).
// Live state ~70 VGPRs; __launch_bounds__(256,4) caps at 128 -> no spill.
__global__ __launch_bounds__(256, 4) void bconv(
        const uint64_t* __restrict__ xb, const float* __restrict__ beta,
        const uint64_t* __restrict__ kb, const float* __restrict__ palpha,
        const float* __restrict__ bias, float* __restrict__ out) {
    int bi = blockIdx.x;             // n*H_ + h
    int n = bi / H_, h = bi % H_;
    int co = threadIdx.x;

    __shared__ __align__(16) uint64_t xs[3 * WP * 4];  // [r][col][word], 5568 B
    __shared__ float brow[3 * WP];
    __shared__ float bS[W_];

    // stage packed bits for padded rows h..h+2 (contiguous in global)
    const uint64_t* xsrc = xb + (size_t)(n * HP + h) * WP * 4;
    for (int i = threadIdx.x; i < 3 * WP * 4; i += 256) xs[i] = xsrc[i];
    const float* bsrc = beta + (size_t)(n * HP + h) * WP;
    for (int i = threadIdx.x; i < 3 * WP; i += 256) brow[i] = bsrc[i];
    __syncthreads();

    // 3x3 window sums of beta (the avg_pool), one thread per output w
    if (threadIdx.x < W_) {
        float s = 0.f;
        #pragma unroll
        for (int r = 0; r < 3; ++r)
            #pragma unroll
            for (int d = 0; d < 3; ++d) s += brow[r * WP + threadIdx.x + d];
        bS[threadIdx.x] = s * (1.f / 9.f);
    }

    // alpha + bias (36 coalesced partial-sum loads, L2-resident)
    float asum = 0.f;
    #pragma unroll
    for (int i = 0; i < 36; ++i) asum += palpha[i * 256 + co];
    float alpha = asum * (1.f / 2304.f);
    float bv = bias[co];
    __syncthreads();   // bS visible

    float* orow = out + (size_t)(n * H_ + h) * W_ * C_ + co;

    for (int chunk = 0; chunk < 4; ++chunk) {   // outputs w in [w0, w0+14)
        int w0 = chunk * 14;
        uint32_t acc[14];
        #pragma unroll
        for (int i = 0; i < 14; ++i) acc[i] = 0;

        for (int jp = 0; jp < 2; ++jp) {        // channel-word pair {2jp,2jp+1}
            uint64_t kr0[9], kr1[9];
            #pragma unroll
            for (int t = 0; t < 9; ++t) {
                kr0[t] = kb[(t * 4 + 2 * jp) * 256 + co];
                kr1[t] = kb[(t * 4 + 2 * jp + 1) * 256 + co];
            }
            #pragma unroll
            for (int xi = 0; xi < 16; ++xi) {   // input columns w0..w0+15
                #pragma unroll
                for (int r = 0; r < 3; ++r) {
                    const uint64_t* px = &xs[(r * WP + w0 + xi) * 4 + 2 * jp];
                    uint64_t x0 = px[0], x1 = px[1];   // one ds_read_b128
                    #pragma unroll
                    for (int kw = 0; kw < 3; ++kw) {
                        int wl = xi - kw;       // compile-time after unroll
                        if (wl >= 0 && wl < 14) {
                            int t = r * 3 + kw;
                            acc[wl] += __popcll(x0 ^ kr0[t]) + __popcll(x1 ^ kr1[t]);
                        }
                    }
                }
            }
        }
        #pragma unroll
        for (int wl = 0; wl < 14; ++wl) {
            int w = w0 + wl;
            float conv = (float)(2304 - 2 * (int)acc[wl]);
            orow[(size_t)w * C_] = conv * bS[w] * alpha + bv;
        }
    }
}

extern "C" void kernel_launch(void* const* d_in, const int* in_sizes, int n_in,
                              void* d_out, int out_size, void* d_ws, size_t ws_size,
                              hipStream_t stream) {
    const float* x    = (const float*)d_in[0];
    const float* k    = (const float*)d_in[1];
    const float* bias = (const float*)d_in[2];
    float* out = (float*)d_out;

    char* ws = (char*)d_ws;
    uint64_t* kb     = (uint64_t*)(ws);             //  73,728 B
    float*    palpha = (float*)(ws + 73728);        //  36,864 B
    uint64_t* xb     = (uint64_t*)(ws + 110592);    // 3,444,736 B
    float*    beta   = (float*)(ws + 3555328);      //   430,592 B (total ~4 MB)

    pack_w<<<36, 256, 0, stream>>>(k, kb, palpha);
    pack_x<<<N_ * HP, 256, 0, stream>>>(x, xb, beta);
    bconv<<<N_ * H_, 256, 0, stream>>>(xb, beta, kb, palpha, bias, out);
}

// Round 3
// 296.598 us; speedup vs baseline: 1.0205x; 1.0205x over previous
//
#include <hip/hip_runtime.h>
#include <cstdint>

#define N_ 32
#define H_ 56
#define W_ 56
#define C_ 256
#define HP 58
#define WP 58

// Channel -> (word, bit) map used by BOTH packers: channel c = 4*b + j lives in
// word j, bit b. The popcount dot-product is invariant to this permutation;
// alpha/beta are plain channel sums, also invariant.

// ---------------- kernel 1: pack weight sign bits + |k| partial sums --------
// grid = 36 blocks (idx = p*4 + j, p = tap in [0,9), j = word in [0,4))
// block = 256 threads (co). Output layout kb[p][co][j] so bconv can load a
// 16B (2-word) pair per tap with one dwordx4.
__global__ __launch_bounds__(256) void pack_w(const float* __restrict__ k,
                                              uint64_t* __restrict__ kb,
                                              float* __restrict__ palpha) {
    int idx = blockIdx.x;            // 0..35
    int p = idx >> 2, j = idx & 3;
    int co = threadIdx.x;
    uint64_t bits = 0;
    float s = 0.f;
    #pragma unroll
    for (int b = 0; b < 64; ++b) {
        float v = k[(p * 256 + 4 * b + j) * 256 + co];   // channel 4b+j
        bits |= (uint64_t)(v > 0.f) << b;
        s += fabsf(v);
    }
    kb[((size_t)p * 256 + co) * 4 + j] = bits;
    palpha[idx * 256 + co] = s;
}

// ---------------- kernel 2: pack input sign bits + beta ---------------------
// grid = N_*HP (one padded row), block = 256 = 4 waves. One float4 load per
// lane covers channels 4*lane..4*lane+3; ballot of component j builds word j
// (bit b = sign(channel 4b+j), matching pack_w). Border pixels: sign bit 0
// (sign(0) = -1 in the reference), beta contribution 0.
__global__ __launch_bounds__(256) void pack_x(const float4* __restrict__ x4,
                                              uint64_t* __restrict__ xb,
                                              float* __restrict__ beta) {
    int bi = blockIdx.x;             // n*HP + y (padded row)
    int n = bi / HP, y = bi % HP;
    int wave = threadIdx.x >> 6, lane = threadIdx.x & 63;
    for (int xc = wave; xc < WP; xc += 4) {
        bool inb = (y >= 1 && y <= H_ && xc >= 1 && xc <= W_);
        float4 v = make_float4(0.f, 0.f, 0.f, 0.f);
        if (inb)
            v = x4[(((size_t)n * H_ + (y - 1)) * W_ + (xc - 1)) * 64 + lane];
        uint64_t m0 = __ballot(v.x > 0.f);
        uint64_t m1 = __ballot(v.y > 0.f);
        uint64_t m2 = __ballot(v.z > 0.f);
        uint64_t m3 = __ballot(v.w > 0.f);
        float s = fabsf(v.x) + fabsf(v.y) + fabsf(v.z) + fabsf(v.w);
        #pragma unroll
        for (int m = 32; m >= 1; m >>= 1) s += __shfl_xor(s, m, 64);
        size_t pix = (size_t)bi * WP + xc;
        if (lane < 4) {
            uint64_t mw = (lane == 0) ? m0 : (lane == 1) ? m1 : (lane == 2) ? m2 : m3;
            xb[pix * 4 + lane] = mw;
        }
        if (lane == 0) beta[pix] = s * (1.f / 256.f);
    }
}

// ---------------- kernel 3: binary conv via xor+popcount --------------------
// grid = (N_*H_, 2), block = 256. Thread = (half, col): half in {0,1} picks
// channel-words {2h, 2h+1}; co = blockIdx.y*128 + col. Per-thread live state
// (kr 36 + acc 14 + pair 4 ~ 72 VGPRs) fits arch VGPRs -> no AGPR shuffling
// (round-2 failure mode). All ds_read_b128 use a chunk-invariant base with
// constant immediate offsets. Halves combine via padded LDS (stride 15).
__global__ __launch_bounds__(256, 4) void bconv(
        const uint64_t* __restrict__ xb, const float* __restrict__ beta,
        const uint64_t* __restrict__ kb, const float* __restrict__ palpha,
        const float* __restrict__ bias, float* __restrict__ out) {
    int bi = blockIdx.x;             // n*H_ + h
    int n = bi / H_, h = bi % H_;
    int tid = threadIdx.x;
    int half = tid >> 7;             // 0/1
    int col = tid & 127;
    int co = (blockIdx.y << 7) | col;

    __shared__ __align__(16) uint64_t xs[3 * WP * 4];   // [r][col][word], 5568 B
    __shared__ float brow[3 * WP];
    __shared__ float bS[W_];
    __shared__ uint32_t pb[128 * 15];                   // padded: free 2-way

    // stage packed bits for padded rows h..h+2 (contiguous, 16B vectors)
    const uint64_t* xsrc = xb + (size_t)(n * HP + h) * WP * 4;
    for (int i = tid; i < 3 * WP * 2; i += 256)
        ((ulonglong2*)xs)[i] = ((const ulonglong2*)xsrc)[i];
    const float* bsrc = beta + (size_t)(n * HP + h) * WP;
    for (int i = tid; i < 3 * WP; i += 256) brow[i] = bsrc[i];
    __syncthreads();

    // 3x3 window sums of beta (the avg_pool), one thread per output w
    if (tid < W_) {
        float s = 0.f;
        #pragma unroll
        for (int r = 0; r < 3; ++r)
            #pragma unroll
            for (int d = 0; d < 3; ++d) s += brow[r * WP + tid + d];
        bS[tid] = s * (1.f / 9.f);
    }

    // this thread's 2 weight words per tap: one 16B load each
    uint64_t kr0[9], kr1[9];
    #pragma unroll
    for (int t = 0; t < 9; ++t) {
        ulonglong2 kp = ((const ulonglong2*)kb)[((size_t)t * 256 + co) * 2 + half];
        kr0[t] = kp.x;
        kr1[t] = kp.y;
    }
    float asum = 0.f;
    #pragma unroll
    for (int i = 0; i < 36; ++i) asum += palpha[i * 256 + co];
    float alpha = asum * (1.f / 2304.f);
    float bv = bias[co];

    for (int chunk = 0; chunk < 4; ++chunk) {   // outputs w in [w0, w0+14)
        int w0 = chunk * 14;
        uint32_t acc[14];
        #pragma unroll
        for (int i = 0; i < 14; ++i) acc[i] = 0;

        // chunk-invariant base; all offsets below are compile-time constants
        const uint64_t* base = &xs[w0 * 4 + 2 * half];
        #pragma unroll
        for (int xi = 0; xi < 16; ++xi) {       // input columns w0..w0+15
            #pragma unroll
            for (int r = 0; r < 3; ++r) {
                uint64_t x0 = base[(r * WP + xi) * 4];      // one ds_read_b128
                uint64_t x1 = base[(r * WP + xi) * 4 + 1];
                #pragma unroll
                for (int kw = 0; kw < 3; ++kw) {
                    int wl = xi - kw;           // compile-time after unroll
                    if (wl >= 0 && wl < 14) {
                        int t = r * 3 + kw;
                        acc[wl] += __popcll(x0 ^ kr0[t]) + __popcll(x1 ^ kr1[t]);
                    }
                }
            }
        }

        __syncthreads();                 // pb safe to overwrite
        if (half == 1) {
            #pragma unroll
            for (int i = 0; i < 14; ++i) pb[col * 15 + i] = acc[i];
        }
        __syncthreads();                 // pb visible (and bS on chunk 0)
        if (half == 0) {
            #pragma unroll
            for (int i = 0; i < 14; ++i) {
                int w = w0 + i;
                int tot = (int)(acc[i] + pb[col * 15 + i]);
                float conv = (float)(2304 - 2 * tot);
                out[((size_t)bi * W_ + w) * C_ + co] = conv * bS[w] * alpha + bv;
            }
        }
    }
}

extern "C" void kernel_launch(void* const* d_in, const int* in_sizes, int n_in,
                              void* d_out, int out_size, void* d_ws, size_t ws_size,
                              hipStream_t stream) {
    const float* x    = (const float*)d_in[0];
    const float* k    = (const float*)d_in[1];
    const float* bias = (const float*)d_in[2];
    float* out = (float*)d_out;

    char* ws = (char*)d_ws;
    uint64_t* kb     = (uint64_t*)(ws);             //  73,728 B  [p][co][word]
    float*    palpha = (float*)(ws + 73728);        //  36,864 B
    uint64_t* xb     = (uint64_t*)(ws + 110592);    // 3,444,736 B
    float*    beta   = (float*)(ws + 3555328);      //   430,592 B (total ~4 MB)

    pack_w<<<36, 256, 0, stream>>>(k, kb, palpha);
    pack_x<<<N_ * HP, 256, 0, stream>>>((const float4*)x, xb, beta);
    bconv<<<dim3(N_ * H_, 2), 256, 0, stream>>>(xb, beta, kb, palpha, bias, out);
}